// Round 8
// baseline (423.821 us; speedup 1.0000x reference)
//
#include <hip/hip_runtime.h>

#define NN 50000
#define NE 1600000
#define NPART 196        // ceil(NN / 256)
#define PSZ 256

typedef _Float16 f16;
typedef __attribute__((ext_vector_type(8))) _Float16 f16x8;
typedef __attribute__((ext_vector_type(4))) float f32x4;

// ---------------- CSR build: locality-aware counting sort ----------------

__global__ __launch_bounds__(256) void part_count(const int* __restrict__ dst,
                                                  unsigned* __restrict__ pcount, int E) {
    __shared__ unsigned hist[NPART];
    for (int i = threadIdx.x; i < NPART; i += 256) hist[i] = 0;
    __syncthreads();
    for (int e = blockIdx.x * 256 + threadIdx.x; e < E; e += gridDim.x * 256)
        atomicAdd(&hist[((unsigned)dst[e]) >> 8], 1u);
    __syncthreads();
    for (int i = threadIdx.x; i < NPART; i += 256) {
        unsigned c = hist[i];
        if (c) atomicAdd(&pcount[i], c);
    }
}

__global__ void part_scan(const unsigned* __restrict__ pcount,
                          unsigned* __restrict__ poff, unsigned* __restrict__ pcursor) {
    const int t = threadIdx.x;
    const int lane = t & 63, wid = t >> 6;
    __shared__ unsigned wsum[4];
    unsigned v = (t < NPART) ? pcount[t] : 0u;
    unsigned x = v;
    #pragma unroll
    for (int s = 1; s < 64; s <<= 1) {
        unsigned tt = __shfl_up(x, s, 64);
        if (lane >= s) x += tt;
    }
    if (lane == 63) wsum[wid] = x;
    __syncthreads();
    if (t == 0) { unsigned s = 0; for (int k = 0; k < 4; ++k) { unsigned tt = wsum[k]; wsum[k] = s; s += tt; } }
    __syncthreads();
    unsigned excl = x - v + wsum[wid];
    if (t <= NPART) { poff[t] = excl; pcursor[t] = excl; }
}

// tmp record: w(f32)<<32 | dstoff(8)<<16 | src(16)
__global__ __launch_bounds__(512) void bucket_scatter(
    const int* __restrict__ dst, const int* __restrict__ src, const float* __restrict__ ew,
    unsigned* __restrict__ pcursor, unsigned long long* __restrict__ tmp, int E) {
    __shared__ unsigned hist[NPART];
    __shared__ unsigned gbase[NPART];
    const int chunk = blockIdx.x * 8192;
    for (int i = threadIdx.x; i < NPART; i += 512) hist[i] = 0;
    __syncthreads();
    #pragma unroll
    for (int r = 0; r < 16; ++r) {
        int e = chunk + threadIdx.x + r * 512;
        if (e < E) atomicAdd(&hist[((unsigned)dst[e]) >> 8], 1u);
    }
    __syncthreads();
    for (int i = threadIdx.x; i < NPART; i += 512) {
        unsigned c = hist[i];
        gbase[i] = c ? atomicAdd(&pcursor[i], c) : 0u;
        hist[i] = 0;
    }
    __syncthreads();
    #pragma unroll
    for (int r = 0; r < 16; ++r) {
        int e = chunk + threadIdx.x + r * 512;
        if (e < E) {
            unsigned d = (unsigned)dst[e];
            unsigned part = d >> 8;
            unsigned rank = atomicAdd(&hist[part], 1u);
            unsigned long long rec =
                ((unsigned long long)__float_as_uint(ew[e]) << 32)
              | ((unsigned long long)(d & 0xffu) << 16)
              | (unsigned)src[e];
            tmp[gbase[part] + rank] = rec;
        }
    }
}

// emit final 4B records: w_f16<<16 | src_u16
__global__ __launch_bounds__(256) void part_sort(
    const unsigned long long* __restrict__ tmp, const unsigned* __restrict__ poff,
    unsigned* __restrict__ edges, unsigned* __restrict__ off,
    float* __restrict__ invdeg, int N) {
    __shared__ unsigned hist[PSZ];
    __shared__ unsigned excl[PSZ];
    __shared__ unsigned wsum[4];
    const int b = blockIdx.x;
    const unsigned e0 = poff[b], e1 = poff[b + 1];
    const int t = threadIdx.x;
    hist[t] = 0;
    __syncthreads();
    for (unsigned i = e0 + t; i < e1; i += 256)
        atomicAdd(&hist[(unsigned)(tmp[i] >> 16) & 0xffu], 1u);
    __syncthreads();
    const unsigned v = hist[t];
    const int lane = t & 63, wid = t >> 6;
    unsigned x = v;
    #pragma unroll
    for (int s = 1; s < 64; s <<= 1) {
        unsigned tt = __shfl_up(x, s, 64);
        if (lane >= s) x += tt;
    }
    if (lane == 63) wsum[wid] = x;
    __syncthreads();
    if (t == 0) { unsigned s = 0; for (int k = 0; k < 4; ++k) { unsigned tt = wsum[k]; wsum[k] = s; s += tt; } }
    __syncthreads();
    const unsigned ex = x - v + wsum[wid];
    excl[t] = ex;
    const int node = b * PSZ + t;
    if (node < N) {
        off[node] = e0 + ex;
        invdeg[node] = v ? 1.0f / (float)v : 0.0f;
    }
    if (b == NPART - 1 && t == 0) off[N] = e1;
    hist[t] = 0;
    __syncthreads();
    for (unsigned i = e0 + t; i < e1; i += 256) {
        unsigned long long rec = tmp[i];
        unsigned doff = (unsigned)(rec >> 16) & 0xffu;
        unsigned r = atomicAdd(&hist[doff], 1u);
        union { f16 h; unsigned short u; } cw;
        cw.h = (f16)__uint_as_float((unsigned)(rec >> 32));
        edges[e0 + excl[doff] + r] = ((unsigned)cw.u << 16) | (unsigned)(rec & 0xffffull);
    }
}

// ---------------- pack f32 [N][128] -> f16 [N][128] ----------------

__global__ __launch_bounds__(256) void pack_x(const float* __restrict__ in,
                                              f16* __restrict__ out, int n8) {
    int i = blockIdx.x * 256 + threadIdx.x;
    if (i < n8) {
        float4 a = ((const float4*)in)[i * 2];
        float4 b = ((const float4*)in)[i * 2 + 1];
        f16x8 h;
        h[0] = (f16)a.x; h[1] = (f16)a.y; h[2] = (f16)a.z; h[3] = (f16)a.w;
        h[4] = (f16)b.x; h[5] = (f16)b.y; h[6] = (f16)b.z; h[7] = (f16)b.w;
        ((f16x8*)out)[i] = h;
    }
}

// ---------------- MFMA GEMM: P = X@Wa^T (f16 slab-major), Q = X@Wh^T + b (f16) -----
// P layout: [NS][NN][32] f16, slab = col>>5.  Q: [NN][OUTH] f16.

template <int OUTH>     // 128 (layers 1/2) or 64 (layer 3)
__global__ __launch_bounds__(256) void gemm_mfma(
    const f16* __restrict__ X, const float* __restrict__ W,
    const float* __restrict__ bias,
    f16* __restrict__ Pout,             // [OUTH/32][NN][32]
    f16* __restrict__ Qout,             // [NN][OUTH] f16
    int N)
{
    const int tile = blockIdx.x * 64;
    const int colbase = blockIdx.y * 64;
    const int t = threadIdx.x;
    const int lane = t & 63;
    const int wv = t >> 6;

    __shared__ f16 Xs[64 * 128];
    __shared__ f16 Ws[64 * 128];

    #pragma unroll
    for (int i = 0; i < 4; ++i) {
        int row = i * 16 + (t >> 4);
        int chunk = t & 15;
        int v = tile + row;
        uint4 val = make_uint4(0u, 0u, 0u, 0u);
        if (v < N) val = ((const uint4*)(X + (size_t)v * 128))[chunk];
        ((uint4*)Xs)[row * 16 + (chunk ^ (row & 7))] = val;
    }
    const int isq = (colbase >= OUTH);
    #pragma unroll
    for (int i = 0; i < 4; ++i) {
        int row = i * 16 + (t >> 4);            // local col
        int chunk = t & 15;
        int c = colbase + row;
        const float* wsrc = W + (size_t)(isq ? c - OUTH : c) * 256 + (isq ? 128 : 0) + chunk * 8;
        float4 wa = *(const float4*)wsrc;
        float4 wb = *(const float4*)(wsrc + 4);
        f16x8 wh;
        wh[0] = (f16)wa.x; wh[1] = (f16)wa.y; wh[2] = (f16)wa.z; wh[3] = (f16)wa.w;
        wh[4] = (f16)wb.x; wh[5] = (f16)wb.y; wh[6] = (f16)wb.z; wh[7] = (f16)wb.w;
        ((f16x8*)Ws)[row * 16 + (chunk ^ (row & 7))] = wh;
    }
    __syncthreads();

    const int lr = lane & 15;
    const int kg = lane >> 4;
    f16x8 afrag[4];
    #pragma unroll
    for (int kb = 0; kb < 4; ++kb) {
        int row = wv * 16 + lr;
        afrag[kb] = ((const f16x8*)Xs)[row * 16 + ((kb * 4 + kg) ^ (row & 7))];
    }
    f32x4 acc[4];
    #pragma unroll
    for (int nt = 0; nt < 4; ++nt)
        #pragma unroll
        for (int j = 0; j < 4; ++j) acc[nt][j] = 0.0f;

    #pragma unroll
    for (int nt = 0; nt < 4; ++nt) {
        int col = nt * 16 + lr;
        #pragma unroll
        for (int kb = 0; kb < 4; ++kb) {
            f16x8 bfrag = ((const f16x8*)Ws)[col * 16 + ((kb * 4 + kg) ^ (col & 7))];
            acc[nt] = __builtin_amdgcn_mfma_f32_16x16x32_f16(afrag[kb], bfrag, acc[nt], 0, 0, 0);
        }
    }

    // epilogue: C/D layout col=lane&15, row=(lane>>4)*4+reg
    #pragma unroll
    for (int nt = 0; nt < 4; ++nt) {
        int c = colbase + nt * 16 + lr;
        #pragma unroll
        for (int j = 0; j < 4; ++j) {
            int v = tile + wv * 16 + kg * 4 + j;
            if (v >= N) continue;
            if (!isq) {
                int sl = c >> 5;
                Pout[((size_t)sl * NN + v) * 32 + (c & 31)] = (f16)acc[nt][j];
            } else {
                int qc = c - OUTH;
                Qout[(size_t)v * OUTH + qc] = (f16)(acc[nt][j] + bias[qc]);
            }
        }
    }
}

// ---------------- group-per-node slab aggregate ----------------
// Block = 256 thr = 4 waves; wave = 16 groups of 4 lanes; group g owns node
// (blockIdx.x*64 + wave*16 + g) and serially walks its own edge list for one
// 32-dim slab (lane = 8 dims, uint4 row read). No cross-lane combine.

template <int NS, bool F16OUT>      // NS slabs of 32 dims; DIM = NS*32
__global__ __launch_bounds__(256) void agg_grp(
    const f16* __restrict__ P,                       // [NS][NN][32]
    const f16* __restrict__ Qh,                      // [NN][DIM] f16
    const unsigned* __restrict__ edges,              // [E] w_f16<<16|src
    const unsigned* __restrict__ off, const float* __restrict__ invdeg,
    void* __restrict__ outv)
{
    constexpr int DIM = NS * 32;
    const int slab = blockIdx.y;
    const int wave = threadIdx.x >> 6;
    const int lane = threadIdx.x & 63;
    const int grp  = lane >> 2;
    const int lr   = lane & 3;
    const int node = blockIdx.x * 64 + wave * 16 + grp;
    const bool valid = (node < NN);

    unsigned s0 = 0, deg = 0;
    if (valid) {
        s0 = off[node];
        deg = off[node + 1] - s0;
    }
    // wave-wide max degree (values uniform within each 4-lane group)
    unsigned md = deg;
    #pragma unroll
    for (int s = 4; s < 64; s <<= 1)
        md = max(md, (unsigned)__shfl_xor((int)md, s, 64));

    const f16* __restrict__ Pb = P + (size_t)slab * NN * 32;
    const unsigned* __restrict__ ep = edges + s0;

    float a[8];
    #pragma unroll
    for (int i = 0; i < 8; ++i) a[i] = 0.f;

    for (unsigned it = 0; it < md; ++it) {
        if (it < deg) {
            unsigned rec = ep[it];
            unsigned srcv = rec & 0xffffu;
            float wv;
            { union { unsigned short u; f16 h; } cw;
              cw.u = (unsigned short)(rec >> 16); wv = (float)cw.h; }
            const uint4 r = *(const uint4*)(Pb + (size_t)srcv * 32 + lr * 8);
            union { uint4 u; f16 h[8]; } c_; c_.u = r;
            #pragma unroll
            for (int i = 0; i < 8; ++i)
                a[i] = fmaf((float)c_.h[i], wv, a[i]);
        }
    }

    if (valid) {
        const float inv = invdeg[node];
        const int cb = slab * 32 + lr * 8;
        f16x8 q = *(const f16x8*)(Qh + (size_t)node * DIM + cb);
        float o[8];
        #pragma unroll
        for (int i = 0; i < 8; ++i)
            o[i] = fmaxf(fmaf(a[i], inv, (float)q[i]), 0.f);
        if (F16OUT) {
            f16x8 h;
            #pragma unroll
            for (int i = 0; i < 8; ++i) h[i] = (f16)o[i];
            *(f16x8*)((f16*)outv + (size_t)node * DIM + cb) = h;
        } else {
            float* out = (float*)outv;
            *(float4*)&out[(size_t)node * DIM + cb]     = make_float4(o[0], o[1], o[2], o[3]);
            *(float4*)&out[(size_t)node * DIM + cb + 4] = make_float4(o[4], o[5], o[6], o[7]);
        }
    }
}

// ---------------- launch ----------------

extern "C" void kernel_launch(void* const* d_in, const int* in_sizes, int n_in,
                              void* d_out, int out_size, void* d_ws, size_t ws_size,
                              hipStream_t stream) {
    const float* n_feat = (const float*)d_in[0];
    const float* ew     = (const float*)d_in[1];
    const int*   src    = (const int*)d_in[2];
    const int*   dst    = (const int*)d_in[3];
    const float* W1 = (const float*)d_in[4];
    const float* b1 = (const float*)d_in[5];
    const float* W2 = (const float*)d_in[6];
    const float* b2 = (const float*)d_in[7];
    const float* W3 = (const float*)d_in[8];
    const float* b3 = (const float*)d_in[9];

    const int N = NN, E = NE;

    uint8_t* w = (uint8_t*)d_ws;
    size_t o = 0;
    auto carve = [&](size_t bytes) { uint8_t* p = w + o; o += (bytes + 255) & ~(size_t)255; return p; };
    unsigned* pcount  = (unsigned*)carve((size_t)NPART * 4);
    unsigned* poff    = (unsigned*)carve((size_t)(NPART + 1) * 4);
    unsigned* pcursor = (unsigned*)carve((size_t)(NPART + 1) * 4);
    unsigned* off     = (unsigned*)carve((size_t)(N + 1) * 4);
    float*    invdeg  = (float*)   carve((size_t)N * 4);
    unsigned* edges   = (unsigned*)carve((size_t)E * 4);         // 4B records
    f16*      Xf      = (f16*)     carve((size_t)N * 128 * 2);
    f16*      H       = (f16*)     carve((size_t)N * 128 * 2);
    f16*      P       = (f16*)     carve((size_t)N * 128 * 2);   // slab-major
    size_t qbytes = (size_t)N * 128 * 2;                          // Qh f16
    size_t tbytes = (size_t)E * 8;                                // tmp 8B recs
    f16*      Qh      = (f16*)     carve(qbytes > tbytes ? qbytes : tbytes);
    unsigned long long* tmp = (unsigned long long*)Qh;  // Qh first written after part_sort

    float* OUT = (float*)d_out;

    // CSR build (counting sort)
    hipMemsetAsync(pcount, 0, (size_t)NPART * 4, stream);
    part_count<<<392, 256, 0, stream>>>(dst, pcount, E);
    part_scan<<<1, 256, 0, stream>>>(pcount, poff, pcursor);
    bucket_scatter<<<(E + 8191) / 8192, 512, 0, stream>>>(dst, src, ew, pcursor, tmp, E);
    part_sort<<<NPART, 256, 0, stream>>>(tmp, poff, edges, off, invdeg, N);

    const int gx = (N + 63) / 64;   // 782, also agg grid (64 nodes/block)

    // layer 1
    pack_x<<<(N * 16 + 255) / 256, 256, 0, stream>>>(n_feat, Xf, N * 16);
    gemm_mfma<128><<<dim3(gx, 4), 256, 0, stream>>>(Xf, W1, b1, P, Qh, N);
    agg_grp<4, true><<<dim3(gx, 4), 256, 0, stream>>>(P, Qh, edges, off, invdeg, H);

    // layer 2
    gemm_mfma<128><<<dim3(gx, 4), 256, 0, stream>>>(H, W2, b2, P, Qh, N);
    agg_grp<4, true><<<dim3(gx, 4), 256, 0, stream>>>(P, Qh, edges, off, invdeg, H);

    // layer 3 (64 dims out, f32)
    gemm_mfma<64><<<dim3(gx, 2), 256, 0, stream>>>(H, W3, b3, P, Qh, N);
    agg_grp<2, false><<<dim3(gx, 2), 256, 0, stream>>>(P, Qh, edges, off, invdeg, OUT);
}

// Round 9
// 273.179 us; speedup vs baseline: 1.5514x; 1.5514x over previous
//
#include <hip/hip_runtime.h>

#define NN 50000
#define NE 1600000
#define NPART 196        // ceil(NN / 256)
#define PSZ 256

typedef _Float16 f16;
typedef __attribute__((ext_vector_type(8))) _Float16 f16x8;
typedef __attribute__((ext_vector_type(4))) float f32x4;

// ---------------- CSR build: locality-aware counting sort ----------------

__global__ __launch_bounds__(256) void part_count(const int* __restrict__ dst,
                                                  unsigned* __restrict__ pcount, int E) {
    __shared__ unsigned hist[NPART];
    for (int i = threadIdx.x; i < NPART; i += 256) hist[i] = 0;
    __syncthreads();
    for (int e = blockIdx.x * 256 + threadIdx.x; e < E; e += gridDim.x * 256)
        atomicAdd(&hist[((unsigned)dst[e]) >> 8], 1u);
    __syncthreads();
    for (int i = threadIdx.x; i < NPART; i += 256) {
        unsigned c = hist[i];
        if (c) atomicAdd(&pcount[i], c);
    }
}

__global__ void part_scan(const unsigned* __restrict__ pcount,
                          unsigned* __restrict__ poff, unsigned* __restrict__ pcursor) {
    const int t = threadIdx.x;
    const int lane = t & 63, wid = t >> 6;
    __shared__ unsigned wsum[4];
    unsigned v = (t < NPART) ? pcount[t] : 0u;
    unsigned x = v;
    #pragma unroll
    for (int s = 1; s < 64; s <<= 1) {
        unsigned tt = __shfl_up(x, s, 64);
        if (lane >= s) x += tt;
    }
    if (lane == 63) wsum[wid] = x;
    __syncthreads();
    if (t == 0) { unsigned s = 0; for (int k = 0; k < 4; ++k) { unsigned tt = wsum[k]; wsum[k] = s; s += tt; } }
    __syncthreads();
    unsigned excl = x - v + wsum[wid];
    if (t <= NPART) { poff[t] = excl; pcursor[t] = excl; }
}

// tmp record: w(f32)<<32 | dstoff(8)<<16 | src(16)
__global__ __launch_bounds__(512) void bucket_scatter(
    const int* __restrict__ dst, const int* __restrict__ src, const float* __restrict__ ew,
    unsigned* __restrict__ pcursor, unsigned long long* __restrict__ tmp, int E) {
    __shared__ unsigned hist[NPART];
    __shared__ unsigned gbase[NPART];
    const int chunk = blockIdx.x * 8192;
    for (int i = threadIdx.x; i < NPART; i += 512) hist[i] = 0;
    __syncthreads();
    #pragma unroll
    for (int r = 0; r < 16; ++r) {
        int e = chunk + threadIdx.x + r * 512;
        if (e < E) atomicAdd(&hist[((unsigned)dst[e]) >> 8], 1u);
    }
    __syncthreads();
    for (int i = threadIdx.x; i < NPART; i += 512) {
        unsigned c = hist[i];
        gbase[i] = c ? atomicAdd(&pcursor[i], c) : 0u;
        hist[i] = 0;
    }
    __syncthreads();
    #pragma unroll
    for (int r = 0; r < 16; ++r) {
        int e = chunk + threadIdx.x + r * 512;
        if (e < E) {
            unsigned d = (unsigned)dst[e];
            unsigned part = d >> 8;
            unsigned rank = atomicAdd(&hist[part], 1u);
            unsigned long long rec =
                ((unsigned long long)__float_as_uint(ew[e]) << 32)
              | ((unsigned long long)(d & 0xffu) << 16)
              | (unsigned)src[e];
            tmp[gbase[part] + rank] = rec;
        }
    }
}

// emit final 4B records: w_f16<<16 | src_u16
__global__ __launch_bounds__(256) void part_sort(
    const unsigned long long* __restrict__ tmp, const unsigned* __restrict__ poff,
    unsigned* __restrict__ edges, unsigned* __restrict__ off,
    float* __restrict__ invdeg, int N) {
    __shared__ unsigned hist[PSZ];
    __shared__ unsigned excl[PSZ];
    __shared__ unsigned wsum[4];
    const int b = blockIdx.x;
    const unsigned e0 = poff[b], e1 = poff[b + 1];
    const int t = threadIdx.x;
    hist[t] = 0;
    __syncthreads();
    for (unsigned i = e0 + t; i < e1; i += 256)
        atomicAdd(&hist[(unsigned)(tmp[i] >> 16) & 0xffu], 1u);
    __syncthreads();
    const unsigned v = hist[t];
    const int lane = t & 63, wid = t >> 6;
    unsigned x = v;
    #pragma unroll
    for (int s = 1; s < 64; s <<= 1) {
        unsigned tt = __shfl_up(x, s, 64);
        if (lane >= s) x += tt;
    }
    if (lane == 63) wsum[wid] = x;
    __syncthreads();
    if (t == 0) { unsigned s = 0; for (int k = 0; k < 4; ++k) { unsigned tt = wsum[k]; wsum[k] = s; s += tt; } }
    __syncthreads();
    const unsigned ex = x - v + wsum[wid];
    excl[t] = ex;
    const int node = b * PSZ + t;
    if (node < N) {
        off[node] = e0 + ex;
        invdeg[node] = v ? 1.0f / (float)v : 0.0f;
    }
    if (b == NPART - 1 && t == 0) off[N] = e1;
    hist[t] = 0;
    __syncthreads();
    for (unsigned i = e0 + t; i < e1; i += 256) {
        unsigned long long rec = tmp[i];
        unsigned doff = (unsigned)(rec >> 16) & 0xffu;
        unsigned r = atomicAdd(&hist[doff], 1u);
        union { f16 h; unsigned short u; } cw;
        cw.h = (f16)__uint_as_float((unsigned)(rec >> 32));
        edges[e0 + excl[doff] + r] = ((unsigned)cw.u << 16) | (unsigned)(rec & 0xffffull);
    }
}

// ---------------- pack f32 [N][128] -> f16 [N][128] ----------------

__global__ __launch_bounds__(256) void pack_x(const float* __restrict__ in,
                                              f16* __restrict__ out, int n8) {
    int i = blockIdx.x * 256 + threadIdx.x;
    if (i < n8) {
        float4 a = ((const float4*)in)[i * 2];
        float4 b = ((const float4*)in)[i * 2 + 1];
        f16x8 h;
        h[0] = (f16)a.x; h[1] = (f16)a.y; h[2] = (f16)a.z; h[3] = (f16)a.w;
        h[4] = (f16)b.x; h[5] = (f16)b.y; h[6] = (f16)b.z; h[7] = (f16)b.w;
        ((f16x8*)out)[i] = h;
    }
}

// ---------------- MFMA GEMM: P = X@Wa^T (f16 row-major), Q = X@Wh^T + b (f16) -----

template <int OUTH>     // 128 (layers 1/2) or 64 (layer 3)
__global__ __launch_bounds__(256) void gemm_mfma(
    const f16* __restrict__ X, const float* __restrict__ W,
    const float* __restrict__ bias,
    f16* __restrict__ Pout,             // [NN][OUTH] f16
    f16* __restrict__ Qout,             // [NN][OUTH] f16
    int N)
{
    const int tile = blockIdx.x * 64;
    const int colbase = blockIdx.y * 64;
    const int t = threadIdx.x;
    const int lane = t & 63;
    const int wv = t >> 6;

    __shared__ f16 Xs[64 * 128];
    __shared__ f16 Ws[64 * 128];

    #pragma unroll
    for (int i = 0; i < 4; ++i) {
        int row = i * 16 + (t >> 4);
        int chunk = t & 15;
        int v = tile + row;
        uint4 val = make_uint4(0u, 0u, 0u, 0u);
        if (v < N) val = ((const uint4*)(X + (size_t)v * 128))[chunk];
        ((uint4*)Xs)[row * 16 + (chunk ^ (row & 7))] = val;
    }
    const int isq = (colbase >= OUTH);
    #pragma unroll
    for (int i = 0; i < 4; ++i) {
        int row = i * 16 + (t >> 4);            // local col
        int chunk = t & 15;
        int c = colbase + row;
        const float* wsrc = W + (size_t)(isq ? c - OUTH : c) * 256 + (isq ? 128 : 0) + chunk * 8;
        float4 wa = *(const float4*)wsrc;
        float4 wb = *(const float4*)(wsrc + 4);
        f16x8 wh;
        wh[0] = (f16)wa.x; wh[1] = (f16)wa.y; wh[2] = (f16)wa.z; wh[3] = (f16)wa.w;
        wh[4] = (f16)wb.x; wh[5] = (f16)wb.y; wh[6] = (f16)wb.z; wh[7] = (f16)wb.w;
        ((f16x8*)Ws)[row * 16 + (chunk ^ (row & 7))] = wh;
    }
    __syncthreads();

    const int lr = lane & 15;
    const int kg = lane >> 4;
    f16x8 afrag[4];
    #pragma unroll
    for (int kb = 0; kb < 4; ++kb) {
        int row = wv * 16 + lr;
        afrag[kb] = ((const f16x8*)Xs)[row * 16 + ((kb * 4 + kg) ^ (row & 7))];
    }
    f32x4 acc[4];
    #pragma unroll
    for (int nt = 0; nt < 4; ++nt)
        #pragma unroll
        for (int j = 0; j < 4; ++j) acc[nt][j] = 0.0f;

    #pragma unroll
    for (int nt = 0; nt < 4; ++nt) {
        int col = nt * 16 + lr;
        #pragma unroll
        for (int kb = 0; kb < 4; ++kb) {
            f16x8 bfrag = ((const f16x8*)Ws)[col * 16 + ((kb * 4 + kg) ^ (col & 7))];
            acc[nt] = __builtin_amdgcn_mfma_f32_16x16x32_f16(afrag[kb], bfrag, acc[nt], 0, 0, 0);
        }
    }

    // epilogue: C/D layout col=lane&15, row=(lane>>4)*4+reg
    #pragma unroll
    for (int nt = 0; nt < 4; ++nt) {
        int c = colbase + nt * 16 + lr;
        #pragma unroll
        for (int j = 0; j < 4; ++j) {
            int v = tile + wv * 16 + kg * 4 + j;
            if (v >= N) continue;
            if (!isq) {
                Pout[(size_t)v * OUTH + c] = (f16)acc[nt][j];
            } else {
                int qc = c - OUTH;
                Qout[(size_t)v * OUTH + qc] = (f16)(acc[nt][j] + bias[qc]);
            }
        }
    }
}

// ---------------- fused aggregate: out = relu(mean_agg(P) + Q) ----------------
// Wave per node. LPR lanes per row (16 -> DIM 128, 8 -> DIM 64), G = 64/LPR
// edges per wave iteration; uint4 row reads; shfl_xor combine; f16 Q.

#define AGG_STEP(REC) {                                                         \
    unsigned srcv = (REC) & 0xffffu;                                            \
    float wvv; { union { unsigned short u; f16 h; } cw;                         \
                 cw.u = (unsigned short)((REC) >> 16); wvv = (float)cw.h; }     \
    const uint4 r = *(const uint4*)(P + (size_t)srcv * DIM + lr * 8);           \
    union { uint4 u; f16 h[8]; } c_; c_.u = r;                                  \
    a[0] = fmaf((float)c_.h[0], wvv, a[0]);                                     \
    a[1] = fmaf((float)c_.h[1], wvv, a[1]);                                     \
    a[2] = fmaf((float)c_.h[2], wvv, a[2]);                                     \
    a[3] = fmaf((float)c_.h[3], wvv, a[3]);                                     \
    a[4] = fmaf((float)c_.h[4], wvv, a[4]);                                     \
    a[5] = fmaf((float)c_.h[5], wvv, a[5]);                                     \
    a[6] = fmaf((float)c_.h[6], wvv, a[6]);                                     \
    a[7] = fmaf((float)c_.h[7], wvv, a[7]); }

template <int LPR, bool F16OUT>
__global__ __launch_bounds__(256) void agg_fused(
    const f16* __restrict__ P,                       // [NN][DIM] f16
    const f16* __restrict__ Qh,                      // [NN][DIM] f16
    const unsigned* __restrict__ edges,              // [E] w_f16<<16|src
    const unsigned* __restrict__ off, const float* __restrict__ invdeg,
    void* __restrict__ outv)
{
    constexpr int DIM = LPR * 8;
    constexpr int G   = 64 / LPR;
    const int node = blockIdx.x * 4 + (threadIdx.x >> 6);
    const int lane = threadIdx.x & 63;
    const int g    = lane / LPR;
    const int lr   = lane % LPR;
    const unsigned s0 = off[node], s1 = off[node + 1];
    const unsigned deg = s1 - s0;
    const float inv = invdeg[node];

    float a[8];
    #pragma unroll
    for (int i = 0; i < 8; ++i) a[i] = 0.f;

    const unsigned* __restrict__ ep = edges + s0 + g;
    const unsigned nfull = deg / G;
    #pragma unroll 8
    for (unsigned it = 0; it < nfull; ++it) {
        unsigned rec = ep[(size_t)it * G];
        AGG_STEP(rec);
    }
    if ((unsigned)g < (deg - nfull * G)) {
        unsigned rec = ep[(size_t)nfull * G];
        AGG_STEP(rec);
    }

    #pragma unroll
    for (int i = 0; i < 8; ++i) {
        a[i] += __shfl_xor(a[i], 32, 64);
        a[i] += __shfl_xor(a[i], 16, 64);
        if (LPR == 8) a[i] += __shfl_xor(a[i], 8, 64);
    }

    if (lane < LPR) {
        f16x8 q = *(const f16x8*)(Qh + (size_t)node * DIM + lr * 8);
        float o[8];
        #pragma unroll
        for (int i = 0; i < 8; ++i)
            o[i] = fmaxf(fmaf(a[i], inv, (float)q[i]), 0.f);
        if (F16OUT) {
            f16x8 h;
            #pragma unroll
            for (int i = 0; i < 8; ++i) h[i] = (f16)o[i];
            *(f16x8*)((f16*)outv + (size_t)node * DIM + lr * 8) = h;
        } else {
            float* out = (float*)outv;
            *(float4*)&out[(size_t)node * DIM + lr * 8]     = make_float4(o[0], o[1], o[2], o[3]);
            *(float4*)&out[(size_t)node * DIM + lr * 8 + 4] = make_float4(o[4], o[5], o[6], o[7]);
        }
    }
}

// ---------------- launch ----------------

extern "C" void kernel_launch(void* const* d_in, const int* in_sizes, int n_in,
                              void* d_out, int out_size, void* d_ws, size_t ws_size,
                              hipStream_t stream) {
    const float* n_feat = (const float*)d_in[0];
    const float* ew     = (const float*)d_in[1];
    const int*   src    = (const int*)d_in[2];
    const int*   dst    = (const int*)d_in[3];
    const float* W1 = (const float*)d_in[4];
    const float* b1 = (const float*)d_in[5];
    const float* W2 = (const float*)d_in[6];
    const float* b2 = (const float*)d_in[7];
    const float* W3 = (const float*)d_in[8];
    const float* b3 = (const float*)d_in[9];

    const int N = NN, E = NE;

    uint8_t* w = (uint8_t*)d_ws;
    size_t o = 0;
    auto carve = [&](size_t bytes) { uint8_t* p = w + o; o += (bytes + 255) & ~(size_t)255; return p; };
    unsigned* pcount  = (unsigned*)carve((size_t)NPART * 4);
    unsigned* poff    = (unsigned*)carve((size_t)(NPART + 1) * 4);
    unsigned* pcursor = (unsigned*)carve((size_t)(NPART + 1) * 4);
    unsigned* off     = (unsigned*)carve((size_t)(N + 1) * 4);
    float*    invdeg  = (float*)   carve((size_t)N * 4);
    unsigned* edges   = (unsigned*)carve((size_t)E * 4);         // 4B records
    f16*      Xf      = (f16*)     carve((size_t)N * 128 * 2);
    f16*      H       = (f16*)     carve((size_t)N * 128 * 2);
    f16*      P       = (f16*)     carve((size_t)N * 128 * 2);   // row-major
    size_t qbytes = (size_t)N * 128 * 2;                          // Qh f16
    size_t tbytes = (size_t)E * 8;                                // tmp 8B recs
    f16*      Qh      = (f16*)     carve(qbytes > tbytes ? qbytes : tbytes);
    unsigned long long* tmp = (unsigned long long*)Qh;  // Qh first written after part_sort

    float* OUT = (float*)d_out;

    // CSR build (counting sort)
    hipMemsetAsync(pcount, 0, (size_t)NPART * 4, stream);
    part_count<<<392, 256, 0, stream>>>(dst, pcount, E);
    part_scan<<<1, 256, 0, stream>>>(pcount, poff, pcursor);
    bucket_scatter<<<(E + 8191) / 8192, 512, 0, stream>>>(dst, src, ew, pcursor, tmp, E);
    part_sort<<<NPART, 256, 0, stream>>>(tmp, poff, edges, off, invdeg, N);

    const int gx = (N + 63) / 64;       // gemm grid
    const int ga = N / 4;               // agg grid (12500)

    // layer 1
    pack_x<<<(N * 16 + 255) / 256, 256, 0, stream>>>(n_feat, Xf, N * 16);
    gemm_mfma<128><<<dim3(gx, 4), 256, 0, stream>>>(Xf, W1, b1, P, Qh, N);
    agg_fused<16, true><<<ga, 256, 0, stream>>>(P, Qh, edges, off, invdeg, H);

    // layer 2
    gemm_mfma<128><<<dim3(gx, 4), 256, 0, stream>>>(H, W2, b2, P, Qh, N);
    agg_fused<16, true><<<ga, 256, 0, stream>>>(P, Qh, edges, off, invdeg, H);

    // layer 3 (64 dims out, f32)
    gemm_mfma<64><<<dim3(gx, 2), 256, 0, stream>>>(H, W3, b3, P, Qh, N);
    agg_fused<8, false><<<ga, 256, 0, stream>>>(P, Qh, edges, off, invdeg, OUT);
}